// Round 6
// baseline (220.061 us; speedup 1.0000x reference)
//
#include <hip/hip_runtime.h>

// YOLO loss: N=4096, S=14, B=2, NCLS=20. Cells = 802816.
// R6: amortize workgroup dispatch. Evidence: R1 (AoS, 4.4x more VMEM line
// traffic) and R5 (coalesced LDS-staged) BOTH run ~66-68us with all pipes
// idle (VALU 13%, BW 1.3 TB/s, occ 33-51%, avg wave lifetime ~34k cyc).
// Invariant: 3136 WGs -> 47 WG/us ~= command-processor WG launch/retire rate.
// Fix: 784 WGs x 4 slabs each (slab = 256 cells), partials in registers,
// one 16B store per block. LDS 11.7KB single-buffered per slab iteration.
// Dispatches: init (detect mask layout), main, reduce(784x4 floats).

#define NCELLS (4096 * 14 * 14)
#define TPB 256
#define SLABS 4
#define NSLAB (NCELLS / TPB)          // 3136 slabs
#define NBLK (NSLAB / SLABS)          // 784 main blocks

// ws layout (floats): [8] mask-mode flag (int); [16 + 4*blk .. +3] per-block
// partials (cls, noobj, contain, reg). 16 + 3136 floats ~= 12.6 KB.

__global__ void yolo_init_kernel(float* ws, const unsigned char* mb) {
    if (threadIdx.x == 0) ((int*)ws)[8] = 0;
    __syncthreads();
    // Detect mask layout: int32 {0,1} has bytes 4k+1..4k+3 == 0; random bool8
    // doesn't. Scan first 4096 slots (16KB; both layouts exceed that).
    int t = threadIdx.x;
    unsigned int found = 0;
#pragma unroll
    for (int k = 0; k < 16; ++k) {
        int slot = t * 16 + k;
        found |= mb[4 * slot + 1] | mb[4 * slot + 2] | mb[4 * slot + 3];
    }
    if (found) atomicOr((int*)ws + 8, 1);  // 1 => bool8 layout
}

__global__ __launch_bounds__(256) void yolo_main_kernel(
    const float* __restrict__ pred,
    const float* __restrict__ tbox,
    const float* __restrict__ tcls,
    const void* __restrict__ mask,
    float* __restrict__ ws) {
    __shared__ float sbox[TPB * 10];  // 10240 B: per-cell box fields
    __shared__ float sm[TPB];         // 1024 B: per-cell mask as float
    __shared__ float red[4][4];
    const int tid = threadIdx.x;
    const int blk = blockIdx.x;
    const int mode = ((const int*)ws)[8];  // uniform

    float cls_a = 0.0f, noobj_a = 0.0f, contain_a = 0.0f, reg_a = 0.0f;

    for (int s = 0; s < SLABS; ++s) {
        const int slab = blk * SLABS + s;        // contiguous region per block
        const int c = slab * TPB + tid;

        // ---- batched coalesced loads for this slab ----
        const float2* gp = (const float2*)(pred + (size_t)slab * (TPB * 30));
        const float2* gc = (const float2*)(tcls + (size_t)slab * (TPB * 20));
        float2 pv[15];
#pragma unroll
        for (int j = 0; j < 15; ++j) pv[j] = gp[tid + TPB * j];
        float2 tv[15];
#pragma unroll
        for (int j = 0; j < 15; ++j) {
            int idx = tid + TPB * j;
            int cc = idx / 15;           // magic-mul
            int p2 = idx - cc * 15;
            int gi = cc * 10 + (p2 >= 5 ? p2 - 5 : 0);  // clamped (dummy if box)
            tv[j] = gc[gi];
        }
        const float4 tb = ((const float4*)tbox)[c];
        float mval;
        if (mode) {
            mval = ((const unsigned char*)mask)[c] ? 1.0f : 0.0f;
        } else {
            mval = ((const int*)mask)[c] ? 1.0f : 0.0f;
        }

        __syncthreads();  // sbox/sm from previous slab fully consumed
        sm[tid] = mval;

        // ---- element-parallel: box chunks -> LDS, cls chunks -> diff ----
#pragma unroll
        for (int j = 0; j < 15; ++j) {
            int idx = tid + TPB * j;
            int cc = idx / 15;
            int p2 = idx - cc * 15;
            if (p2 < 5) {
                ((float2*)(sbox + cc * 10))[p2] = pv[j];
            }
        }
        __syncthreads();
        float cls_s = 0.0f;
#pragma unroll
        for (int j = 0; j < 15; ++j) {
            int idx = tid + TPB * j;
            int cc = idx / 15;
            int p2 = idx - cc * 15;
            if (p2 >= 5) {
                float d1 = pv[j].x - tv[j].x, d2 = pv[j].y - tv[j].y;
                cls_s += sm[cc] * (d1 * d1 + d2 * d2);
            }
        }
        cls_a += cls_s;

        // ---- per-cell box computation (cell = tid) ----
        const float* bx = sbox + tid * 10;  // [x0,y0,w0,h0,c0, x1,y1,w1,h1,c1]
        float2 q0 = ((const float2*)bx)[0];
        float2 q1 = ((const float2*)bx)[1];
        float2 q2 = ((const float2*)bx)[2];
        float2 q3 = ((const float2*)bx)[3];
        float2 q4 = ((const float2*)bx)[4];
        float x0 = q0.x, y0 = q0.y, w0 = q1.x, h0 = q1.y, c0 = q2.x;
        float x1 = q2.y, y1 = q3.x, w1 = q3.y, h1 = q4.x, c1 = q4.y;
        float m = mval;

        noobj_a += (1.0f - m) * (c0 * c0 + c1 * c1);

        float at = (tb.z - tb.x) * (tb.w - tb.y);
        float iou0, iou1;
        {
            float x = x0 * (1.0f / 14.0f), y = y0 * (1.0f / 14.0f);
            float iw = fmaxf(fminf(x + w0 * 0.5f, tb.z) - fmaxf(x - w0 * 0.5f, tb.x), 0.0f);
            float ih = fmaxf(fminf(y + h0 * 0.5f, tb.w) - fmaxf(y - h0 * 0.5f, tb.y), 0.0f);
            float inter = iw * ih;
            iou0 = inter / (w0 * h0 + at - inter);
        }
        {
            float x = x1 * (1.0f / 14.0f), y = y1 * (1.0f / 14.0f);
            float iw = fmaxf(fminf(x + w1 * 0.5f, tb.z) - fmaxf(x - w1 * 0.5f, tb.x), 0.0f);
            float ih = fmaxf(fminf(y + h1 * 0.5f, tb.w) - fmaxf(y - h1 * 0.5f, tb.y), 0.0f);
            float inter = iw * ih;
            iou1 = inter / (w1 * h1 + at - inter);
        }
        bool sel = iou1 > iou0;  // jnp.argmax: first max wins
        float bxv = sel ? x1 : x0, byv = sel ? y1 : y0;
        float bwv = sel ? w1 : w0, bhv = sel ? h1 : h0;
        float bcv = sel ? c1 : c0;

        contain_a += m * (bcv - 1.0f) * (bcv - 1.0f);

        float dx = bxv - tb.x, dy = byv - tb.y;
        float dw = sqrtf(bwv) - sqrtf(tb.z);
        float dh = sqrtf(bhv) - sqrtf(tb.w);
        reg_a += m * (dx * dx + dy * dy + dw * dw + dh * dh);
    }

    // ---- reduction: wave64 shuffle -> LDS -> private partial slot ----
#pragma unroll
    for (int off = 32; off > 0; off >>= 1) {
        cls_a += __shfl_down(cls_a, off, 64);
        noobj_a += __shfl_down(noobj_a, off, 64);
        contain_a += __shfl_down(contain_a, off, 64);
        reg_a += __shfl_down(reg_a, off, 64);
    }
    int lane = tid & 63;
    int wid = tid >> 6;
    if (lane == 0) {
        red[wid][0] = cls_a;
        red[wid][1] = noobj_a;
        red[wid][2] = contain_a;
        red[wid][3] = reg_a;
    }
    __syncthreads();
    if (tid < 4) {
        float v = red[0][tid] + red[1][tid] + red[2][tid] + red[3][tid];
        ws[16 + 4 * blk + tid] = v;  // plain store, zero contention
    }
}

__global__ __launch_bounds__(256) void yolo_reduce_kernel(
    const float* __restrict__ ws, float* __restrict__ out) {
    const float4* part = (const float4*)(ws + 16);  // one float4 per block
    float s0 = 0.0f, s1 = 0.0f, s2 = 0.0f, s3 = 0.0f;
    for (int i = threadIdx.x; i < NBLK; i += 256) {
        float4 p = part[i];
        s0 += p.x; s1 += p.y; s2 += p.z; s3 += p.w;
    }
#pragma unroll
    for (int off = 32; off > 0; off >>= 1) {
        s0 += __shfl_down(s0, off, 64);
        s1 += __shfl_down(s1, off, 64);
        s2 += __shfl_down(s2, off, 64);
        s3 += __shfl_down(s3, off, 64);
    }
    __shared__ float red[4][4];
    int lane = threadIdx.x & 63;
    int wid = threadIdx.x >> 6;
    if (lane == 0) {
        red[wid][0] = s0;
        red[wid][1] = s1;
        red[wid][2] = s2;
        red[wid][3] = s3;
    }
    __syncthreads();
    if (threadIdx.x == 0) {
        const float inv_n = 1.0f / 4096.0f;
        float cls = (red[0][0] + red[1][0] + red[2][0] + red[3][0]) * inv_n;
        float noobj = (red[0][1] + red[1][1] + red[2][1] + red[3][1]) * inv_n;
        float contain = (red[0][2] + red[1][2] + red[2][2] + red[3][2]) * inv_n;
        float reg = (red[0][3] + red[1][3] + red[2][3] + red[3][3]) * inv_n;
        out[0] = cls + 0.5f * noobj + 5.0f * reg + contain;
        out[1] = reg;
        out[2] = contain;
        out[3] = noobj;
        out[4] = cls;
    }
}

extern "C" void kernel_launch(void* const* d_in, const int* in_sizes, int n_in,
                              void* d_out, int out_size, void* d_ws,
                              size_t ws_size, hipStream_t stream) {
    const float* pred = (const float*)d_in[0];
    const float* tbox = (const float*)d_in[1];
    const float* tcls = (const float*)d_in[2];
    const void* mask = d_in[3];
    float* ws = (float*)d_ws;
    float* out = (float*)d_out;

    yolo_init_kernel<<<1, 256, 0, stream>>>(ws, (const unsigned char*)mask);
    yolo_main_kernel<<<NBLK, TPB, 0, stream>>>(pred, tbox, tcls, mask, ws);
    yolo_reduce_kernel<<<1, 256, 0, stream>>>(ws, out);
}